// Round 1
// baseline (2934.893 us; speedup 1.0000x reference)
//
#include <hip/hip_runtime.h>
#include <cmath>

#define B_   2
#define S_   2048
#define H_   2304
#define NH_  8
#define HD_  256
#define NKV_ 4
#define WIN_ 512

// ---------------------------------------------------------------------------
// Tiled fp32 GEMM: C[M,N] = A[M,K] @ B[K,N], all row-major.
// Requires M%64==0, N%64==0, K%16==0 (true for all four calls).
// 64x64 tile, 256 threads, 4x4 micro-tile per thread.
// ---------------------------------------------------------------------------
__launch_bounds__(256)
__global__ void gemm_f32(const float* __restrict__ A, const float* __restrict__ Bm,
                         float* __restrict__ C, int M, int N, int K) {
  __shared__ float As[16][68];   // [k][m], +4 pad keeps b128 alignment & banks spread
  __shared__ float Bs[16][64];   // [k][n]
  const int t  = threadIdx.x;
  const int bm = blockIdx.y * 64;
  const int bn = blockIdx.x * 64;

  const int arow = t >> 2;              // 0..63
  const int ak   = (t & 3) << 2;        // 0,4,8,12
  const int brow = t >> 4;              // 0..15
  const int bcol = (t & 15) << 2;       // 0..60
  const int crow = (t >> 4) << 2;       // 0..60
  const int ccol = (t & 15) << 2;       // 0..60

  const float* Ap = A  + (long long)(bm + arow) * K + ak;
  const float* Bp = Bm + (long long)brow * N + bn + bcol;

  float acc[4][4];
#pragma unroll
  for (int i = 0; i < 4; ++i)
#pragma unroll
    for (int j = 0; j < 4; ++j) acc[i][j] = 0.f;

  for (int k0 = 0; k0 < K; k0 += 16) {
    float4 a = *(const float4*)(Ap + k0);
    float4 b = *(const float4*)(Bp + (long long)k0 * N);
    __syncthreads();   // previous iter's LDS reads done before overwrite
    As[ak + 0][arow] = a.x;
    As[ak + 1][arow] = a.y;
    As[ak + 2][arow] = a.z;
    As[ak + 3][arow] = a.w;
    *(float4*)&Bs[brow][bcol] = b;
    __syncthreads();
#pragma unroll
    for (int kk = 0; kk < 16; ++kk) {
      float4 av = *(const float4*)&As[kk][crow];
      float4 bv = *(const float4*)&Bs[kk][ccol];
      acc[0][0] = fmaf(av.x, bv.x, acc[0][0]);
      acc[0][1] = fmaf(av.x, bv.y, acc[0][1]);
      acc[0][2] = fmaf(av.x, bv.z, acc[0][2]);
      acc[0][3] = fmaf(av.x, bv.w, acc[0][3]);
      acc[1][0] = fmaf(av.y, bv.x, acc[1][0]);
      acc[1][1] = fmaf(av.y, bv.y, acc[1][1]);
      acc[1][2] = fmaf(av.y, bv.z, acc[1][2]);
      acc[1][3] = fmaf(av.y, bv.w, acc[1][3]);
      acc[2][0] = fmaf(av.z, bv.x, acc[2][0]);
      acc[2][1] = fmaf(av.z, bv.y, acc[2][1]);
      acc[2][2] = fmaf(av.z, bv.z, acc[2][2]);
      acc[2][3] = fmaf(av.z, bv.w, acc[2][3]);
      acc[3][0] = fmaf(av.w, bv.x, acc[3][0]);
      acc[3][1] = fmaf(av.w, bv.y, acc[3][1]);
      acc[3][2] = fmaf(av.w, bv.z, acc[3][2]);
      acc[3][3] = fmaf(av.w, bv.w, acc[3][3]);
    }
  }

#pragma unroll
  for (int ii = 0; ii < 4; ++ii) {
    float4 o = make_float4(acc[ii][0], acc[ii][1], acc[ii][2], acc[ii][3]);
    *(float4*)(C + (long long)(bm + crow + ii) * N + bn + ccol) = o;
  }
}

// ---------------------------------------------------------------------------
// In-place RoPE on Qb [B*S, NH, HD] and Kb [B*S, NKV, HD].
// One thread per (bs, head, d) pair with d in [0,128).
// ---------------------------------------------------------------------------
__global__ void rope_kernel(float* __restrict__ Qb, float* __restrict__ Kb,
                            const int* __restrict__ pos) {
  const int idx  = blockIdx.x * blockDim.x + threadIdx.x;
  const int d    = idx & 127;
  const int rest = idx >> 7;
  const int head = rest % (NH_ + NKV_);
  const int bs   = rest / (NH_ + NKV_);
  if (bs >= B_ * S_) return;

  const float p    = (float)pos[bs];
  // inv_freq = 10000^(-2d/HD) = exp(-d * ln(10000)/128)
  const float invf = expf(-(float)d * (9.210340371976184f / 128.0f));
  const float ang  = p * invf;
  const float c  = cosf(ang);
  const float sn = sinf(ang);

  float* base = (head < NH_)
                    ? (Qb + ((long long)bs * NH_ + head) * HD_)
                    : (Kb + ((long long)bs * NKV_ + (head - NH_)) * HD_);
  const float x1 = base[d];
  const float x2 = base[d + 128];
  base[d]       = x1 * c - x2 * sn;   // q*cos + rotate_half(q)*sin, first half
  base[d + 128] = x2 * c + x1 * sn;   // second half
}

// ---------------------------------------------------------------------------
// Sliding-window causal GQA attention with tanh softcap.
// One wave (64 lanes) per query; lane l owns head dims [4l, 4l+4).
// Layouts: Qb/AO: [B*S, NH, HD]; Kb/Vb: [B*S, NKV, HD].
// Softcapped logits are bounded in [-50,50] -> exp without max-subtraction
// stays in [2e-22, 5e21]: no online max needed.
// ---------------------------------------------------------------------------
__launch_bounds__(256)
__global__ void attn_kernel(const float* __restrict__ Qb, const float* __restrict__ Kb,
                            const float* __restrict__ Vb, float* __restrict__ AO) {
  const int lane = threadIdx.x & 63;
  const int wv   = threadIdx.x >> 6;
  const long long qid = (long long)blockIdx.x * 4 + wv;   // over B*NH*S
  const int i  = (int)(qid & (S_ - 1));
  const int bh = (int)(qid >> 11);       // S_ = 2048 = 1<<11
  const int h  = bh & (NH_ - 1);
  const int b  = bh >> 3;                // NH_ = 8
  const int hk = h >> 1;                 // NH/NKV = 2

  const float4 q = ((const float4*)(Qb + (((long long)b * S_ + i) * NH_ + h) * HD_))[lane];
  const float* kb = Kb + ((long long)b * S_ * NKV_ + hk) * HD_;
  const float* vb = Vb + ((long long)b * S_ * NKV_ + hk) * HD_;
  const int rowstride = NKV_ * HD_;      // 1024 floats between consecutive positions

  int j0 = i - (WIN_ - 1);
  if (j0 < 0) j0 = 0;

  float l = 0.f;
  float4 acc = make_float4(0.f, 0.f, 0.f, 0.f);

  for (int j = j0; j <= i; ++j) {
    const float4 kk = ((const float4*)(kb + (long long)j * rowstride))[lane];
    float d = q.x * kk.x + q.y * kk.y + q.z * kk.z + q.w * kk.w;
#pragma unroll
    for (int off = 32; off > 0; off >>= 1) d += __shfl_xor(d, off, 64);
    // logit = tanh((d/16)/50)*50 ; tanh(x) = (e^{2x}-1)/(e^{2x}+1)
    float x = d * (2.0f / 800.0f);
    x = fminf(fmaxf(x, -30.f), 30.f);
    const float t  = __expf(x);
    const float sc = 50.f * __fdividef(t - 1.f, t + 1.f);
    const float p  = __expf(sc);         // in [2e-22, 5e21], safe in fp32
    const float4 vv = ((const float4*)(vb + (long long)j * rowstride))[lane];
    l += p;
    acc.x = fmaf(p, vv.x, acc.x);
    acc.y = fmaf(p, vv.y, acc.y);
    acc.z = fmaf(p, vv.z, acc.z);
    acc.w = fmaf(p, vv.w, acc.w);
  }

  const float inv = 1.0f / l;
  const float4 o = make_float4(acc.x * inv, acc.y * inv, acc.z * inv, acc.w * inv);
  ((float4*)(AO + (((long long)b * S_ + i) * NH_ + h) * HD_))[lane] = o;
}

// ---------------------------------------------------------------------------
extern "C" void kernel_launch(void* const* d_in, const int* in_sizes, int n_in,
                              void* d_out, int out_size, void* d_ws, size_t ws_size,
                              hipStream_t stream) {
  const float* X   = (const float*)d_in[0];   // hidden_states [B,S,H]
  // d_in[1] = attention_mask (pure causal; enforced analytically, not read)
  const int*   pos = (const int*)d_in[2];     // position_ids [B,S]
  const float* Wq  = (const float*)d_in[3];   // [H, NH*HD]
  const float* Wk  = (const float*)d_in[4];   // [H, NKV*HD]
  const float* Wv  = (const float*)d_in[5];   // [H, NKV*HD]
  const float* Wo  = (const float*)d_in[6];   // [NH*HD, H]
  float* out = (float*)d_out;

  const int M = B_ * S_;                      // 4096
  float* Qb = (float*)d_ws;                   // [4096, 2048]
  float* Kb = Qb + (size_t)M * (NH_ * HD_);   // [4096, 1024]
  float* Vb = Kb + (size_t)M * (NKV_ * HD_);  // [4096, 1024]
  float* AO = Vb + (size_t)M * (NKV_ * HD_);  // [4096, 2048]

  dim3 blk(256);
  // QKV projections
  gemm_f32<<<dim3((NH_ * HD_) / 64,  M / 64), blk, 0, stream>>>(X, Wq, Qb, M, NH_ * HD_,  H_);
  gemm_f32<<<dim3((NKV_ * HD_) / 64, M / 64), blk, 0, stream>>>(X, Wk, Kb, M, NKV_ * HD_, H_);
  gemm_f32<<<dim3((NKV_ * HD_) / 64, M / 64), blk, 0, stream>>>(X, Wv, Vb, M, NKV_ * HD_, H_);
  // RoPE in place on Q and K
  const int pairs = B_ * S_ * (NH_ + NKV_) * (HD_ / 2);   // 6,291,456
  rope_kernel<<<pairs / 256, blk, 0, stream>>>(Qb, Kb, pos);
  // Attention
  attn_kernel<<<(B_ * NH_ * S_) / 4, blk, 0, stream>>>(Qb, Kb, Vb, AO);
  // Output projection
  gemm_f32<<<dim3(H_ / 64, M / 64), blk, 0, stream>>>(AO, Wo, out, M, H_, NH_ * HD_);
}

// Round 2
// 1725.157 us; speedup vs baseline: 1.7012x; 1.7012x over previous
//
#include <hip/hip_runtime.h>
#include <cmath>

#define B_   2
#define S_   2048
#define H_   2304
#define NH_  8
#define HD_  256
#define NKV_ 4
#define WIN_ 512

typedef unsigned short ushort_t;
typedef __attribute__((ext_vector_type(8))) short bf16x8;   // 8 bf16 = 4 VGPRs
typedef __attribute__((ext_vector_type(4))) float floatx4;

// round-to-nearest-even fp32 -> bf16
__device__ __forceinline__ unsigned short f2bf(float f) {
  unsigned u = __builtin_bit_cast(unsigned, f);
  u += 0x7fff + ((u >> 16) & 1);
  return (unsigned short)(u >> 16);
}

// async global->LDS, 16 B per lane. LDS dest is wave-uniform base + lane*16.
__device__ __forceinline__ void gl2lds16(const void* g, void* l) {
  __builtin_amdgcn_global_load_lds(
      (const __attribute__((address_space(1))) unsigned int*)g,
      (__attribute__((address_space(3))) unsigned int*)l, 16, 0, 0);
}

// ---------------------------------------------------------------------------
// Elementwise fp32 -> bf16 cast (4 elems/thread).
// ---------------------------------------------------------------------------
__global__ void cast_bf16(const float* __restrict__ in, ushort_t* __restrict__ out) {
  const int i = blockIdx.x * 256 + threadIdx.x;
  float4 v = ((const float4*)in)[i];
  ushort4 o;
  o.x = f2bf(v.x); o.y = f2bf(v.y); o.z = f2bf(v.z); o.w = f2bf(v.w);
  ((ushort4*)out)[i] = o;
}

// ---------------------------------------------------------------------------
// W[K,N] fp32 -> Wt[N,K] bf16 (32x32 LDS tiles, 256 threads).
// ---------------------------------------------------------------------------
__global__ void transpose_cast(const float* __restrict__ W, ushort_t* __restrict__ Wt,
                               int K, int N) {
  __shared__ float t[32][33];
  const int lx = threadIdx.x & 31, ly = threadIdx.x >> 5;   // ly 0..7
  const int n0 = blockIdx.x * 32, k0 = blockIdx.y * 32;
#pragma unroll
  for (int i = 0; i < 4; ++i)
    t[ly + i * 8][lx] = W[(long long)(k0 + ly + i * 8) * N + n0 + lx];
  __syncthreads();
#pragma unroll
  for (int i = 0; i < 4; ++i)
    Wt[(long long)(n0 + ly + i * 8) * K + k0 + lx] = f2bf(t[lx][ly + i * 8]);
}

// ---------------------------------------------------------------------------
// bf16 MFMA GEMM (m97 structure): C[M,N] fp32 = A[M,K] @ Bt[N,K]^T, bf16 in.
// 128x128 tile, BK=32, 256 thr = 4 waves (2x2 of 64x64), 16x16x32 MFMA.
// Requires M%128==0, N%128==0, K%32==0; rows 16B-aligned (K%8==0).
// A-frag: lane holds A[m=lane&15][k=(lane>>4)*8+j]; B-frag dual (from Bt).
// C/D: col=lane&15, row=(lane>>4)*4+reg.
// ---------------------------------------------------------------------------
__launch_bounds__(256)
__global__ void gemm_bt_bf16(const ushort_t* __restrict__ A,   // [M,K] bf16
                             const ushort_t* __restrict__ Bt,  // [N,K] bf16
                             float* __restrict__ C, int M, int N, int K) {
  __shared__ ushort_t As[128 * 32];   // [m][k] row-major, no pad (global_load_lds)
  __shared__ ushort_t Bs[128 * 32];   // [n][k]
  const int tid = threadIdx.x, lane = tid & 63, wid = tid >> 6;
  const int bm = blockIdx.y * 128, bn = blockIdx.x * 128;
  const int wm = (wid >> 1) * 64, wn = (wid & 1) * 64;

  floatx4 acc[4][4] = {};

  // staging: wave wid loads 32 rows (2 instrs x 16 rows), lane -> (row, 8-elem chunk)
  const int srow = wid * 32 + (lane >> 2);
  const int scol = (lane & 3) * 8;
  const long long aBase = (long long)(bm + srow) * K + scol;
  const long long bBase = (long long)(bn + srow) * K + scol;
  ushort_t* AsW = &As[(wid * 32) * 32];   // wave-uniform LDS dests
  ushort_t* BsW = &Bs[(wid * 32) * 32];

  const int fo = (lane & 15) * 32 + (lane >> 4) * 8;  // fragment LDS offset base

  for (int k0 = 0; k0 < K; k0 += 32) {
    __syncthreads();   // prior iter's LDS reads complete
    gl2lds16(A + aBase + k0,           AsW);
    gl2lds16(A + aBase + k0 + 16 * K,  AsW + 16 * 32);
    gl2lds16(Bt + bBase + k0,          BsW);
    gl2lds16(Bt + bBase + k0 + 16 * K, BsW + 16 * 32);
    __syncthreads();   // vmcnt(0) drain + barrier

    bf16x8 af[4], bfr[4];
#pragma unroll
    for (int i = 0; i < 4; ++i) {
      af[i]  = *(const bf16x8*)&As[(wm + i * 16) * 32 + fo];
      bfr[i] = *(const bf16x8*)&Bs[(wn + i * 16) * 32 + fo];
    }
#pragma unroll
    for (int i = 0; i < 4; ++i)
#pragma unroll
      for (int j = 0; j < 4; ++j)
        acc[i][j] = __builtin_amdgcn_mfma_f32_16x16x32_bf16(af[i], bfr[j], acc[i][j], 0, 0, 0);
  }

  const int r0 = (lane >> 4) * 4, c0 = lane & 15;
#pragma unroll
  for (int i = 0; i < 4; ++i)
#pragma unroll
    for (int j = 0; j < 4; ++j) {
      float* Cp = C + (long long)(bm + wm + i * 16 + r0) * N + bn + wn + j * 16 + c0;
#pragma unroll
      for (int r = 0; r < 4; ++r) Cp[(long long)r * N] = acc[i][j][r];
    }
}

// ---------------------------------------------------------------------------
// In-place RoPE on Qb [B*S, NH, HD] and Kb [B*S, NKV, HD] (fp32).
// ---------------------------------------------------------------------------
__global__ void rope_kernel(float* __restrict__ Qb, float* __restrict__ Kb,
                            const int* __restrict__ pos) {
  const int idx  = blockIdx.x * blockDim.x + threadIdx.x;
  const int d    = idx & 127;
  const int rest = idx >> 7;
  const int head = rest % (NH_ + NKV_);
  const int bs   = rest / (NH_ + NKV_);
  if (bs >= B_ * S_) return;

  const float p    = (float)pos[bs];
  const float invf = expf(-(float)d * (9.210340371976184f / 128.0f));
  const float ang  = p * invf;
  const float c  = cosf(ang);
  const float sn = sinf(ang);

  float* base = (head < NH_)
                    ? (Qb + ((long long)bs * NH_ + head) * HD_)
                    : (Kb + ((long long)bs * NKV_ + (head - NH_)) * HD_);
  const float x1 = base[d];
  const float x2 = base[d + 128];
  base[d]       = x1 * c - x2 * sn;
  base[d + 128] = x2 * c + x1 * sn;
}

// ---------------------------------------------------------------------------
// Sliding-window causal GQA attention, fp32 math, bf16 output (for out-proj).
// One wave per query; lane owns 4 head dims. Softcapped logits in [-50,50]
// -> exp safe without running max.
// ---------------------------------------------------------------------------
__launch_bounds__(256)
__global__ void attn_kernel(const float* __restrict__ Qb, const float* __restrict__ Kb,
                            const float* __restrict__ Vb, ushort_t* __restrict__ AOb) {
  const int lane = threadIdx.x & 63;
  const int wv   = threadIdx.x >> 6;
  const long long qid = (long long)blockIdx.x * 4 + wv;   // over B*NH*S
  const int i  = (int)(qid & (S_ - 1));
  const int bh = (int)(qid >> 11);
  const int h  = bh & (NH_ - 1);
  const int b  = bh >> 3;
  const int hk = h >> 1;

  const float4 q = ((const float4*)(Qb + (((long long)b * S_ + i) * NH_ + h) * HD_))[lane];
  const float* kb = Kb + ((long long)b * S_ * NKV_ + hk) * HD_;
  const float* vb = Vb + ((long long)b * S_ * NKV_ + hk) * HD_;
  const int rowstride = NKV_ * HD_;

  int j0 = i - (WIN_ - 1);
  if (j0 < 0) j0 = 0;

  float l = 0.f;
  float4 acc = make_float4(0.f, 0.f, 0.f, 0.f);

  for (int j = j0; j <= i; ++j) {
    const float4 kk = ((const float4*)(kb + (long long)j * rowstride))[lane];
    float d = q.x * kk.x + q.y * kk.y + q.z * kk.z + q.w * kk.w;
#pragma unroll
    for (int off = 32; off > 0; off >>= 1) d += __shfl_xor(d, off, 64);
    float x = d * (2.0f / 800.0f);
    x = fminf(fmaxf(x, -30.f), 30.f);
    const float t  = __expf(x);
    const float sc = 50.f * __fdividef(t - 1.f, t + 1.f);
    const float p  = __expf(sc);
    const float4 vv = ((const float4*)(vb + (long long)j * rowstride))[lane];
    l += p;
    acc.x = fmaf(p, vv.x, acc.x);
    acc.y = fmaf(p, vv.y, acc.y);
    acc.z = fmaf(p, vv.z, acc.z);
    acc.w = fmaf(p, vv.w, acc.w);
  }

  const float inv = 1.0f / l;
  ushort4 o;
  o.x = f2bf(acc.x * inv);
  o.y = f2bf(acc.y * inv);
  o.z = f2bf(acc.z * inv);
  o.w = f2bf(acc.w * inv);
  ((ushort4*)(AOb + (((long long)b * S_ + i) * NH_ + h) * HD_))[lane] = o;
}

// ---------------------------------------------------------------------------
extern "C" void kernel_launch(void* const* d_in, const int* in_sizes, int n_in,
                              void* d_out, int out_size, void* d_ws, size_t ws_size,
                              hipStream_t stream) {
  const float* X   = (const float*)d_in[0];
  const int*   pos = (const int*)d_in[2];
  const float* Wq  = (const float*)d_in[3];   // [H, NH*HD]
  const float* Wk  = (const float*)d_in[4];   // [H, NKV*HD]
  const float* Wv  = (const float*)d_in[5];   // [H, NKV*HD]
  const float* Wo  = (const float*)d_in[6];   // [NH*HD, H]
  float* out = (float*)d_out;

  const int M  = B_ * S_;        // 4096
  const int NQ = NH_ * HD_;      // 2048
  const int NK = NKV_ * HD_;     // 1024

  char* w = (char*)d_ws;
  float* Qb = (float*)w;                     w += (size_t)M * NQ * 4;   // 32 MB
  float* Kb = (float*)w;                     w += (size_t)M * NK * 4;   // 16 MB
  float* Vb = (float*)w;                     w += (size_t)M * NK * 4;   // 16 MB
  ushort_t* AOb = (ushort_t*)w;              w += (size_t)M * NQ * 2;   // 16 MB
  ushort_t* Xb  = (ushort_t*)w;              w += (size_t)M * H_ * 2;   // 18 MB
  ushort_t* Wqt = (ushort_t*)w;              w += (size_t)NQ * H_ * 2;  // 9.4 MB
  ushort_t* Wkt = (ushort_t*)w;              w += (size_t)NK * H_ * 2;  // 4.7 MB
  ushort_t* Wvt = (ushort_t*)w;              w += (size_t)NK * H_ * 2;  // 4.7 MB
  ushort_t* Wot = (ushort_t*)w;              w += (size_t)H_ * NQ * 2;  // 9.4 MB

  dim3 blk(256);

  // casts + weight transposes
  cast_bf16<<<(M * H_) / 1024, blk, 0, stream>>>(X, Xb);
  transpose_cast<<<dim3(NQ / 32, H_ / 32), blk, 0, stream>>>(Wq, Wqt, H_, NQ);
  transpose_cast<<<dim3(NK / 32, H_ / 32), blk, 0, stream>>>(Wk, Wkt, H_, NK);
  transpose_cast<<<dim3(NK / 32, H_ / 32), blk, 0, stream>>>(Wv, Wvt, H_, NK);
  transpose_cast<<<dim3(H_ / 32, NQ / 32), blk, 0, stream>>>(Wo, Wot, NQ, H_);

  // QKV projections (bf16 MFMA)
  gemm_bt_bf16<<<dim3(NQ / 128, M / 128), blk, 0, stream>>>(Xb, Wqt, Qb, M, NQ, H_);
  gemm_bt_bf16<<<dim3(NK / 128, M / 128), blk, 0, stream>>>(Xb, Wkt, Kb, M, NK, H_);
  gemm_bt_bf16<<<dim3(NK / 128, M / 128), blk, 0, stream>>>(Xb, Wvt, Vb, M, NK, H_);

  // RoPE (fp32, in place)
  const int pairs = B_ * S_ * (NH_ + NKV_) * (HD_ / 2);
  rope_kernel<<<pairs / 256, blk, 0, stream>>>(Qb, Kb, pos);

  // attention (fp32 math, bf16 out)
  attn_kernel<<<(B_ * NH_ * S_) / 4, blk, 0, stream>>>(Qb, Kb, Vb, AOb);

  // output projection (bf16 MFMA, fp32 out)
  gemm_bt_bf16<<<dim3(H_ / 128, M / 128), blk, 0, stream>>>(AOb, Wot, out, M, H_, NQ);
}

// Round 3
// 492.912 us; speedup vs baseline: 5.9542x; 3.4999x over previous
//
#include <hip/hip_runtime.h>
#include <cmath>

#define B_   2
#define S_   2048
#define H_   2304
#define NH_  8
#define HD_  256
#define NKV_ 4
#define WIN_ 512

typedef unsigned short ushort_t;
typedef __attribute__((ext_vector_type(8))) short bf16x8;   // 8 bf16 = 4 VGPRs
typedef __attribute__((ext_vector_type(4))) float floatx4;

// round-to-nearest-even fp32 -> bf16
__device__ __forceinline__ unsigned short f2bf(float f) {
  unsigned u = __builtin_bit_cast(unsigned, f);
  u += 0x7fff + ((u >> 16) & 1);
  return (unsigned short)(u >> 16);
}

// async global->LDS, 16 B per lane. LDS dest is wave-uniform base + lane*16.
__device__ __forceinline__ void gl2lds16(const void* g, void* l) {
  __builtin_amdgcn_global_load_lds(
      (const __attribute__((address_space(1))) unsigned int*)g,
      (__attribute__((address_space(3))) unsigned int*)l, 16, 0, 0);
}

// ---------------------------------------------------------------------------
// Elementwise fp32 -> bf16 cast (4 elems/thread).
// ---------------------------------------------------------------------------
__global__ void cast_bf16(const float* __restrict__ in, ushort_t* __restrict__ out) {
  const int i = blockIdx.x * 256 + threadIdx.x;
  float4 v = ((const float4*)in)[i];
  ushort4 o;
  o.x = f2bf(v.x); o.y = f2bf(v.y); o.z = f2bf(v.z); o.w = f2bf(v.w);
  ((ushort4*)out)[i] = o;
}

// ---------------------------------------------------------------------------
// W[K,N] fp32 -> Wt[N,K] bf16 (32x32 LDS tiles, 256 threads).
// ---------------------------------------------------------------------------
__global__ void transpose_cast(const float* __restrict__ W, ushort_t* __restrict__ Wt,
                               int K, int N) {
  __shared__ float t[32][33];
  const int lx = threadIdx.x & 31, ly = threadIdx.x >> 5;   // ly 0..7
  const int n0 = blockIdx.x * 32, k0 = blockIdx.y * 32;
#pragma unroll
  for (int i = 0; i < 4; ++i)
    t[ly + i * 8][lx] = W[(long long)(k0 + ly + i * 8) * N + n0 + lx];
  __syncthreads();
#pragma unroll
  for (int i = 0; i < 4; ++i)
    Wt[(long long)(n0 + ly + i * 8) * K + k0 + lx] = f2bf(t[lx][ly + i * 8]);
}

// ---------------------------------------------------------------------------
// bf16 MFMA GEMM (m97 structure): C[M,N] fp32 = A[M,K] @ Bt[N,K]^T, bf16 in.
// ---------------------------------------------------------------------------
__launch_bounds__(256)
__global__ void gemm_bt_bf16(const ushort_t* __restrict__ A,   // [M,K] bf16
                             const ushort_t* __restrict__ Bt,  // [N,K] bf16
                             float* __restrict__ C, int M, int N, int K) {
  __shared__ ushort_t As[128 * 32];
  __shared__ ushort_t Bs[128 * 32];
  const int tid = threadIdx.x, lane = tid & 63, wid = tid >> 6;
  const int bm = blockIdx.y * 128, bn = blockIdx.x * 128;
  const int wm = (wid >> 1) * 64, wn = (wid & 1) * 64;

  floatx4 acc[4][4] = {};

  const int srow = wid * 32 + (lane >> 2);
  const int scol = (lane & 3) * 8;
  const long long aBase = (long long)(bm + srow) * K + scol;
  const long long bBase = (long long)(bn + srow) * K + scol;
  ushort_t* AsW = &As[(wid * 32) * 32];
  ushort_t* BsW = &Bs[(wid * 32) * 32];

  const int fo = (lane & 15) * 32 + (lane >> 4) * 8;

  for (int k0 = 0; k0 < K; k0 += 32) {
    __syncthreads();
    gl2lds16(A + aBase + k0,           AsW);
    gl2lds16(A + aBase + k0 + 16 * K,  AsW + 16 * 32);
    gl2lds16(Bt + bBase + k0,          BsW);
    gl2lds16(Bt + bBase + k0 + 16 * K, BsW + 16 * 32);
    __syncthreads();

    bf16x8 af[4], bfr[4];
#pragma unroll
    for (int i = 0; i < 4; ++i) {
      af[i]  = *(const bf16x8*)&As[(wm + i * 16) * 32 + fo];
      bfr[i] = *(const bf16x8*)&Bs[(wn + i * 16) * 32 + fo];
    }
#pragma unroll
    for (int i = 0; i < 4; ++i)
#pragma unroll
      for (int j = 0; j < 4; ++j)
        acc[i][j] = __builtin_amdgcn_mfma_f32_16x16x32_bf16(af[i], bfr[j], acc[i][j], 0, 0, 0);
  }

  const int r0 = (lane >> 4) * 4, c0 = lane & 15;
#pragma unroll
  for (int i = 0; i < 4; ++i)
#pragma unroll
    for (int j = 0; j < 4; ++j) {
      float* Cp = C + (long long)(bm + wm + i * 16 + r0) * N + bn + wn + j * 16 + c0;
#pragma unroll
      for (int r = 0; r < 4; ++r) Cp[(long long)r * N] = acc[i][j][r];
    }
}

// ---------------------------------------------------------------------------
// RoPE + cast + relayout for Q and K.
//   Qf [B*S][NH*256] fp32  -> Q16 [B][NH][S][256] bf16, scaled by 1/16
//   Kf [B*S][NKV*256] fp32 -> K16 [B][NKV][S][256] bf16
// grid: x = bs (4096), y = head (12: 0..7 Q, 8..11 K); block = 256 (d).
// ---------------------------------------------------------------------------
__global__ void qk_prep(const float* __restrict__ Qf, const float* __restrict__ Kf,
                        const int* __restrict__ pos,
                        ushort_t* __restrict__ Q16, ushort_t* __restrict__ K16) {
  const int d = threadIdx.x;
  const int bs = blockIdx.x;
  const int head = blockIdx.y;
  const int b = bs >> 11, q = bs & (S_ - 1);
  const int dh = d & 127;
  const float pp   = (float)pos[bs];
  const float invf = __expf(-(float)dh * (9.210340371976184f / 128.0f));
  const float ang  = pp * invf;
  const float c = cosf(ang), sn = sinf(ang);
  if (head < NH_) {
    const float* base = Qf + (size_t)bs * (NH_ * HD_) + head * HD_;
    const float x = base[d], y = base[d ^ 128];
    const float o = (d < 128) ? (x * c - y * sn) : (x * c + y * sn);
    Q16[((size_t)(b * NH_ + head) * S_ + q) * HD_ + d] = f2bf(o * 0.0625f);
  } else {
    const int hkk = head - NH_;
    const float* base = Kf + (size_t)bs * (NKV_ * HD_) + hkk * HD_;
    const float x = base[d], y = base[d ^ 128];
    const float o = (d < 128) ? (x * c - y * sn) : (x * c + y * sn);
    K16[((size_t)(b * NKV_ + hkk) * S_ + q) * HD_ + d] = f2bf(o);
  }
}

// ---------------------------------------------------------------------------
// V transpose: Vf [B*S][NKV*256] fp32 -> Vt16 [B][NKV][256][S] bf16.
// grid: (S/32, 256/32, B*NKV), block 256.
// ---------------------------------------------------------------------------
__global__ void v_prep(const float* __restrict__ Vf, ushort_t* __restrict__ Vt16) {
  __shared__ float tile[32][33];
  const int k0 = blockIdx.x * 32, d0 = blockIdx.y * 32;
  const int b = blockIdx.z >> 2, hk = blockIdx.z & 3;
  const int lx = threadIdx.x & 31, ly = threadIdx.x >> 5;
#pragma unroll
  for (int i = 0; i < 4; ++i)
    tile[ly + 8 * i][lx] =
        Vf[(size_t)(b * S_ + k0 + ly + 8 * i) * (NKV_ * HD_) + hk * HD_ + d0 + lx];
  __syncthreads();
#pragma unroll
  for (int i = 0; i < 4; ++i)
    Vt16[((size_t)(b * NKV_ + hk) * HD_ + d0 + ly + 8 * i) * S_ + k0 + lx] =
        f2bf(tile[lx][ly + 8 * i]);
}

// ---------------------------------------------------------------------------
// MFMA flash attention, sliding-window causal GQA + tanh softcap.
// Block: 64 queries x 1 head; 4 waves, 16 queries/wave. 32-key rounds.
// S = Q@K^T via mfma (A=Q frags in regs, B=K rows from LDS);
// softcap+exp+mask in C-layout; P through wave-private LDS;
// O^T = V^T @ P^T via mfma (A=V^T rows from LDS, B=P^T).
// Softcapped logits in [-50,50] -> unnormalized exp accumulation, single
// normalization at the end (no online max / rescale).
// XOR chunk swizzles (K: key&31, V: (dim>>1)&3, P: (q>>1)&3) keep LDS frag
// reads ~2-4 way.
// ---------------------------------------------------------------------------
__launch_bounds__(256, 2)
__global__ void attn_mfma(const ushort_t* __restrict__ Q16,   // [B][NH][S][256]
                          const ushort_t* __restrict__ K16,   // [B][NKV][S][256]
                          const ushort_t* __restrict__ Vt16,  // [B][NKV][256][S]
                          ushort_t* __restrict__ AOb) {       // [B][S][NH][256]
  __shared__ ushort_t Ks[32 * 256];    // [key][dim], chunk-swizzled
  __shared__ ushort_t Vts[256 * 32];   // [dim][key], chunk-swizzled
  __shared__ ushort_t Ps[4][16 * 32];  // per-wave P [q][key], chunk-swizzled
  __shared__ float rsb[4][16];

  const int lane = threadIdx.x & 63, w = threadIdx.x >> 6;
  const int l15 = lane & 15, lq = lane >> 4;
  const int qb = blockIdx.x * 64;
  const int h = blockIdx.y, b = blockIdx.z;
  const int hk = h >> 1;

  const ushort_t* Qh = Q16 + ((size_t)(b * NH_ + h) * S_) * HD_;
  const ushort_t* Kh = K16 + ((size_t)(b * NKV_ + hk) * S_) * HD_;
  const ushort_t* Vh = Vt16 + ((size_t)(b * NKV_ + hk) * HD_) * S_;

  const int qw = qb + w * 16;   // wave's first query

  // Q A-fragments, held in registers for the whole kernel
  bf16x8 afq[8];
  {
    const ushort_t* qr = Qh + (size_t)(qw + l15) * HD_ + lq * 8;
#pragma unroll
    for (int kd = 0; kd < 8; ++kd) afq[kd] = *(const bf16x8*)(qr + kd * 32);
  }

  floatx4 acc[16] = {};                 // acc[t][r] = O[q=l15][dim=t*16+lq*4+r]
  float rs[4] = {0.f, 0.f, 0.f, 0.f};   // row-sum partials for q=lq*4+r

  int kb0 = qb - (WIN_ - 1);
  if (kb0 < 0) kb0 = 0;
  kb0 &= ~31;

  const int ksp = lane & 31, ksr = lane >> 5;   // K staging: chunk pos, row parity
  const int vsp = lane & 3,  vsr = lane >> 2;   // V staging: chunk pos, row offset

  for (int kb = kb0; kb < qb + 64; kb += 32) {
    __syncthreads();
    // stage K keys [kb + w*8, +8): 4 instrs x (2 rows of 512 B)
#pragma unroll
    for (int i = 0; i < 4; ++i) {
      const int kl = w * 8 + 2 * i + ksr;
      gl2lds16(Kh + (size_t)(kb + kl) * HD_ + (ksp ^ (kl & 31)) * 8,
               &Ks[(w * 8 + 2 * i) * 256]);
    }
    // stage V^T dims [w*64, +64): 4 instrs x (16 rows of 64 B)
#pragma unroll
    for (int i = 0; i < 4; ++i) {
      const int dl = w * 64 + 16 * i + vsr;
      gl2lds16(Vh + (size_t)dl * S_ + kb + (vsp ^ ((dl >> 1) & 3)) * 8,
               &Vts[(w * 64 + 16 * i) * 32]);
    }
    __syncthreads();

    if (kb <= qw + 15 && kb + 31 >= qw - (WIN_ - 1)) {
      ushort_t* Pw = Ps[w];
#pragma unroll
      for (int kt = 0; kt < 2; ++kt) {
        floatx4 sacc = {};
        const int keyl = kt * 16 + l15;
        const int krow = keyl * 256;
        const int ksw = keyl & 31;
#pragma unroll
        for (int kd = 0; kd < 8; ++kd) {
          bf16x8 bk = *(const bf16x8*)&Ks[krow + ((kd * 4 + lq) ^ ksw) * 8];
          sacc = __builtin_amdgcn_mfma_f32_16x16x32_bf16(afq[kd], bk, sacc, 0, 0, 0);
        }
        const int keyg = kb + keyl;
#pragma unroll
        for (int r = 0; r < 4; ++r) {
          const int qg = qw + lq * 4 + r;
          // p = exp(50*tanh(s/50)), s already includes the 1/16 scale (in Q)
          const float t = __expf(sacc[r] * 0.04f);
          const float L = 50.f - __fdividef(100.f, t + 1.f);
          float p = __expf(L);
          p = (keyg <= qg && keyg >= qg - (WIN_ - 1)) ? p : 0.f;
          rs[r] += p;
          const int ql = lq * 4 + r;
          const int ch = kt * 2 + (l15 >> 3);
          Pw[ql * 32 + ((ch ^ ((ql >> 1) & 3)) * 8) + (l15 & 7)] = f2bf(p);
        }
      }
      // wave-private LDS: drain DS queue before cross-lane read (no barrier)
      asm volatile("s_waitcnt lgkmcnt(0)" ::: "memory");

      const bf16x8 bp = *(const bf16x8*)&Pw[l15 * 32 + ((lq ^ ((l15 >> 1) & 3)) * 8)];
      const int vsw = (l15 >> 1) & 3;   // (d_l>>1)&3 is t-independent
#pragma unroll
      for (int t = 0; t < 16; ++t) {
        bf16x8 av = *(const bf16x8*)&Vts[(t * 16 + l15) * 32 + ((lq ^ vsw) * 8)];
        acc[t] = __builtin_amdgcn_mfma_f32_16x16x32_bf16(av, bp, acc[t], 0, 0, 0);
      }
    }
  }

  // full row sums: reduce across the 16 lanes of each quad-row group
#pragma unroll
  for (int r = 0; r < 4; ++r) {
    rs[r] += __shfl_xor(rs[r], 1, 64);
    rs[r] += __shfl_xor(rs[r], 2, 64);
    rs[r] += __shfl_xor(rs[r], 4, 64);
    rs[r] += __shfl_xor(rs[r], 8, 64);
  }
  if (l15 == 0) {
#pragma unroll
    for (int r = 0; r < 4; ++r) rsb[w][lq * 4 + r] = rs[r];
  }
  asm volatile("s_waitcnt lgkmcnt(0)" ::: "memory");
  __builtin_amdgcn_wave_barrier();
  const float inv = 1.0f / rsb[w][l15];

  const size_t ob = ((size_t)(b * S_ + qw + l15) * NH_ + h) * HD_;
#pragma unroll
  for (int t = 0; t < 16; ++t) {
    ushort4 o;
    o.x = f2bf(acc[t][0] * inv);
    o.y = f2bf(acc[t][1] * inv);
    o.z = f2bf(acc[t][2] * inv);
    o.w = f2bf(acc[t][3] * inv);
    *(ushort4*)&AOb[ob + t * 16 + lq * 4] = o;
  }
}

// ---------------------------------------------------------------------------
extern "C" void kernel_launch(void* const* d_in, const int* in_sizes, int n_in,
                              void* d_out, int out_size, void* d_ws, size_t ws_size,
                              hipStream_t stream) {
  const float* X   = (const float*)d_in[0];
  const int*   pos = (const int*)d_in[2];
  const float* Wq  = (const float*)d_in[3];
  const float* Wk  = (const float*)d_in[4];
  const float* Wv  = (const float*)d_in[5];
  const float* Wo  = (const float*)d_in[6];
  float* out = (float*)d_out;

  const int M  = B_ * S_;        // 4096
  const int NQ = NH_ * HD_;      // 2048
  const int NK = NKV_ * HD_;     // 1024

  char* w = (char*)d_ws;
  float* Qb = (float*)w;          w += (size_t)M * NQ * 4;     // 32 MB (AOb aliases)
  float* Kb = (float*)w;          w += (size_t)M * NK * 4;     // 16 MB
  float* Vb = (float*)w;          w += (size_t)M * NK * 4;     // 16 MB
  ushort_t* Xb = (ushort_t*)w;    w += (size_t)M * H_ * 2;     // 18 MB (Q16 aliases)
  ushort_t* Wqt = (ushort_t*)w;   w += (size_t)NQ * H_ * 2;
  ushort_t* Wkt = (ushort_t*)w;   w += (size_t)NK * H_ * 2;
  ushort_t* Wvt = (ushort_t*)w;   w += (size_t)NK * H_ * 2;
  ushort_t* Wot = (ushort_t*)w;   w += (size_t)H_ * NQ * 2;
  ushort_t* K16 = (ushort_t*)w;   w += (size_t)B_ * NKV_ * S_ * HD_ * 2;  // 8 MB
  ushort_t* Vt16 = (ushort_t*)w;  w += (size_t)B_ * NKV_ * S_ * HD_ * 2;  // 8 MB
  // aliases (strictly ordered uses: Xb dead after GEMMs, Qb dead after qk_prep)
  ushort_t* Q16 = Xb;             // 16 MB <= 18 MB
  ushort_t* AOb = (ushort_t*)Qb;  // 16 MB <= 32 MB

  dim3 blk(256);

  cast_bf16<<<(M * H_) / 1024, blk, 0, stream>>>(X, Xb);
  transpose_cast<<<dim3(NQ / 32, H_ / 32), blk, 0, stream>>>(Wq, Wqt, H_, NQ);
  transpose_cast<<<dim3(NK / 32, H_ / 32), blk, 0, stream>>>(Wk, Wkt, H_, NK);
  transpose_cast<<<dim3(NK / 32, H_ / 32), blk, 0, stream>>>(Wv, Wvt, H_, NK);
  transpose_cast<<<dim3(H_ / 32, NQ / 32), blk, 0, stream>>>(Wo, Wot, NQ, H_);

  gemm_bt_bf16<<<dim3(NQ / 128, M / 128), blk, 0, stream>>>(Xb, Wqt, Qb, M, NQ, H_);
  gemm_bt_bf16<<<dim3(NK / 128, M / 128), blk, 0, stream>>>(Xb, Wkt, Kb, M, NK, H_);
  gemm_bt_bf16<<<dim3(NK / 128, M / 128), blk, 0, stream>>>(Xb, Wvt, Vb, M, NK, H_);

  qk_prep<<<dim3(M, NH_ + NKV_), blk, 0, stream>>>(Qb, Kb, pos, Q16, K16);
  v_prep<<<dim3(S_ / 32, HD_ / 32, B_ * NKV_), blk, 0, stream>>>(Vb, Vt16);

  attn_mfma<<<dim3(S_ / 64, NH_, B_), blk, 0, stream>>>(Q16, K16, Vt16, AOb);

  gemm_bt_bf16<<<dim3(H_ / 128, M / 128), blk, 0, stream>>>(AOb, Wot, out, M, H_, NQ);
}

// Round 4
// 420.078 us; speedup vs baseline: 6.9865x; 1.1734x over previous
//
#include <hip/hip_runtime.h>
#include <cmath>

#define B_   2
#define S_   2048
#define H_   2304
#define NH_  8
#define HD_  256
#define NKV_ 4
#define WIN_ 512
#define QKVW 4096   // fused QKV output row width (8+4+4 heads * 256)

typedef unsigned short ushort_t;
typedef __attribute__((ext_vector_type(8))) short bf16x8;   // 8 bf16 = 4 VGPRs
typedef __attribute__((ext_vector_type(4))) float floatx4;

// round-to-nearest-even fp32 -> bf16
__device__ __forceinline__ unsigned short f2bf(float f) {
  unsigned u = __builtin_bit_cast(unsigned, f);
  u += 0x7fff + ((u >> 16) & 1);
  return (unsigned short)(u >> 16);
}
__device__ __forceinline__ float bf2f(ushort_t v) {
  unsigned u = (unsigned)v << 16;
  return __builtin_bit_cast(float, u);
}

// async global->LDS, 16 B per lane. LDS dest is wave-uniform base + lane*16.
__device__ __forceinline__ void gl2lds16(const void* g, void* l) {
  __builtin_amdgcn_global_load_lds(
      (const __attribute__((address_space(1))) unsigned int*)g,
      (__attribute__((address_space(3))) unsigned int*)l, 16, 0, 0);
}

// ---------------------------------------------------------------------------
// Elementwise fp32 -> bf16 cast (4 elems/thread).
// ---------------------------------------------------------------------------
__global__ void cast_bf16(const float* __restrict__ in, ushort_t* __restrict__ out) {
  const int i = blockIdx.x * 256 + threadIdx.x;
  float4 v = ((const float4*)in)[i];
  ushort4 o;
  o.x = f2bf(v.x); o.y = f2bf(v.y); o.z = f2bf(v.z); o.w = f2bf(v.w);
  ((ushort4*)out)[i] = o;
}

// ---------------------------------------------------------------------------
// W[K,N] fp32 -> Wt[N,K] bf16 (32x32 LDS tiles, 256 threads).
// ---------------------------------------------------------------------------
__global__ void transpose_cast(const float* __restrict__ W, ushort_t* __restrict__ Wt,
                               int K, int N) {
  __shared__ float t[32][33];
  const int lx = threadIdx.x & 31, ly = threadIdx.x >> 5;   // ly 0..7
  const int n0 = blockIdx.x * 32, k0 = blockIdx.y * 32;
#pragma unroll
  for (int i = 0; i < 4; ++i)
    t[ly + i * 8][lx] = W[(long long)(k0 + ly + i * 8) * N + n0 + lx];
  __syncthreads();
#pragma unroll
  for (int i = 0; i < 4; ++i)
    Wt[(long long)(n0 + ly + i * 8) * K + k0 + lx] = f2bf(t[lx][ly + i * 8]);
}

// ---------------------------------------------------------------------------
// bf16 MFMA GEMM (m97 structure + XOR bank-swizzle): C[M,N] = A[M,K]@Bt[N,K]^T.
// 128x128 tile, BK=32, 4 waves (2x2 of 64x64), 16x16x32 MFMA.
// LDS layout: row m of the tile stores its 4 16B-chunks permuted by
// slot = chunk ^ ((m>>1)&3) -- staging loads global chunk (c ^ key) into
// HW-pinned slot c; frag reads slot (lq ^ (l15>>1)&3). 16-lane ds_read_b128
// phases then cover all 8 bank-quads exactly 2x (2-way = free, m136).
// OUT_BF16: epilogue writes bf16 (scalar 2B stores), else fp32.
// ---------------------------------------------------------------------------
template <bool OUT_BF16>
__launch_bounds__(256)
__global__ void gemm_bt(const ushort_t* __restrict__ A,   // [M,K] bf16
                        const ushort_t* __restrict__ Bt,  // [N,K] bf16
                        void* __restrict__ Cv, int M, int N, int K) {
  __shared__ ushort_t As[128 * 32];
  __shared__ ushort_t Bs[128 * 32];
  const int tid = threadIdx.x, lane = tid & 63, wid = tid >> 6;
  const int bm = blockIdx.y * 128, bn = blockIdx.x * 128;
  const int wm = (wid >> 1) * 64, wn = (wid & 1) * 64;

  floatx4 acc[4][4] = {};

  // staging: lane -> (row r, chunk c); global col swizzled by key(r)
  const int r = lane >> 2, c = lane & 3;
  const int skey = (r >> 1) & 3;
  const int scol = (c ^ skey) * 8;
  const int srow = wid * 32 + r;
  const long long aBase = (long long)(bm + srow) * K + scol;
  const long long bBase = (long long)(bn + srow) * K + scol;
  ushort_t* AsW = &As[(wid * 32) * 32];
  ushort_t* BsW = &Bs[(wid * 32) * 32];

  const int l15 = lane & 15, lq = lane >> 4;
  const int fo = l15 * 32 + (lq ^ ((l15 >> 1) & 3)) * 8;   // swizzled frag offset

  for (int k0 = 0; k0 < K; k0 += 32) {
    __syncthreads();
    gl2lds16(A + aBase + k0,           AsW);
    gl2lds16(A + aBase + k0 + 16 * K,  AsW + 16 * 32);
    gl2lds16(Bt + bBase + k0,          BsW);
    gl2lds16(Bt + bBase + k0 + 16 * K, BsW + 16 * 32);
    __syncthreads();

    bf16x8 af[4], bfr[4];
#pragma unroll
    for (int i = 0; i < 4; ++i) {
      af[i]  = *(const bf16x8*)&As[(wm + i * 16) * 32 + fo];
      bfr[i] = *(const bf16x8*)&Bs[(wn + i * 16) * 32 + fo];
    }
#pragma unroll
    for (int i = 0; i < 4; ++i)
#pragma unroll
      for (int j = 0; j < 4; ++j)
        acc[i][j] = __builtin_amdgcn_mfma_f32_16x16x32_bf16(af[i], bfr[j], acc[i][j], 0, 0, 0);
  }

  const int r0 = lq * 4, c0 = l15;
#pragma unroll
  for (int i = 0; i < 4; ++i)
#pragma unroll
    for (int j = 0; j < 4; ++j) {
      const long long base = (long long)(bm + wm + i * 16 + r0) * N + bn + wn + j * 16 + c0;
      if (OUT_BF16) {
        ushort_t* Cp = (ushort_t*)Cv + base;
#pragma unroll
        for (int rr = 0; rr < 4; ++rr) Cp[(long long)rr * N] = f2bf(acc[i][j][rr]);
      } else {
        float* Cp = (float*)Cv + base;
#pragma unroll
        for (int rr = 0; rr < 4; ++rr) Cp[(long long)rr * N] = acc[i][j][rr];
      }
    }
}

// ---------------------------------------------------------------------------
// In-place RoPE on QKV16 [B*S][4096] bf16 (Q cols 0..2047, K cols 2048..3071).
// Also folds the 1/16 attention scale into Q. V region untouched.
// grid (B*S, 6), block 256: gid in [0,1536) -> head 0..11, d 0..127.
// ---------------------------------------------------------------------------
__global__ void rope_inplace(ushort_t* __restrict__ QKV16, const int* __restrict__ pos) {
  const int bs  = blockIdx.x;
  const int gid = blockIdx.y * 256 + threadIdx.x;
  const int head = gid >> 7;          // 0..11
  const int d    = gid & 127;
  const float pp   = (float)pos[bs];
  const float invf = __expf(-(float)d * (9.210340371976184f / 128.0f));
  const float ang  = pp * invf;
  const float cc = cosf(ang), sn = sinf(ang);
  ushort_t* base = QKV16 + (size_t)bs * QKVW + head * HD_;
  const float x1 = bf2f(base[d]);
  const float x2 = bf2f(base[d + 128]);
  float o1 = x1 * cc - x2 * sn;
  float o2 = x2 * cc + x1 * sn;
  if (head < NH_) { o1 *= 0.0625f; o2 *= 0.0625f; }   // fold 1/sqrt(256) into Q
  base[d]       = f2bf(o1);
  base[d + 128] = f2bf(o2);
}

// ---------------------------------------------------------------------------
// V transpose: QKV16 V region [bs][3072 + hk*256 + d] bf16 -> Vt16 [B][NKV][256][S].
// grid (S/32, 256/32, B*NKV), block 256.
// ---------------------------------------------------------------------------
__global__ void v_prep(const ushort_t* __restrict__ QKV16, ushort_t* __restrict__ Vt16) {
  __shared__ ushort_t tile[32][33];
  const int k0 = blockIdx.x * 32, d0 = blockIdx.y * 32;
  const int b = blockIdx.z >> 2, hk = blockIdx.z & 3;
  const int lx = threadIdx.x & 31, ly = threadIdx.x >> 5;
#pragma unroll
  for (int i = 0; i < 4; ++i)
    tile[ly + 8 * i][lx] =
        QKV16[(size_t)(b * S_ + k0 + ly + 8 * i) * QKVW + 3072 + hk * HD_ + d0 + lx];
  __syncthreads();
#pragma unroll
  for (int i = 0; i < 4; ++i)
    Vt16[((size_t)(b * NKV_ + hk) * HD_ + d0 + ly + 8 * i) * S_ + k0 + lx] =
        tile[lx][ly + 8 * i];
}

// ---------------------------------------------------------------------------
// MFMA flash attention, sliding-window causal GQA + tanh softcap.
// Q/K read directly from QKV16 [bs][4096] (row stride QKVW); V from Vt16.
// Block: 64 queries x 1 head; 4 waves, 16 queries/wave; 32-key rounds.
// Softcapped logits in [-50,50] -> unnormalized exp accumulation, single
// normalization at the end.
// ---------------------------------------------------------------------------
__launch_bounds__(256, 2)
__global__ void attn_mfma(const ushort_t* __restrict__ QKV16,  // [B*S][4096]
                          const ushort_t* __restrict__ Vt16,   // [B][NKV][256][S]
                          ushort_t* __restrict__ AOb) {        // [B][S][NH][256]
  __shared__ ushort_t Ks[32 * 256];    // [key][dim], chunk-swizzled
  __shared__ ushort_t Vts[256 * 32];   // [dim][key], chunk-swizzled
  __shared__ ushort_t Ps[4][16 * 32];  // per-wave P [q][key], chunk-swizzled
  __shared__ float rsb[4][16];

  const int lane = threadIdx.x & 63, w = threadIdx.x >> 6;
  const int l15 = lane & 15, lq = lane >> 4;
  const int qb = blockIdx.x * 64;
  const int h = blockIdx.y, b = blockIdx.z;
  const int hk = h >> 1;

  const ushort_t* Qh = QKV16 + (size_t)b * S_ * QKVW + h * HD_;
  const ushort_t* Kh = QKV16 + (size_t)b * S_ * QKVW + 2048 + hk * HD_;
  const ushort_t* Vh = Vt16 + ((size_t)(b * NKV_ + hk) * HD_) * S_;

  const int qw = qb + w * 16;   // wave's first query

  bf16x8 afq[8];
  {
    const ushort_t* qr = Qh + (size_t)(qw + l15) * QKVW + lq * 8;
#pragma unroll
    for (int kd = 0; kd < 8; ++kd) afq[kd] = *(const bf16x8*)(qr + kd * 32);
  }

  floatx4 acc[16] = {};
  float rs[4] = {0.f, 0.f, 0.f, 0.f};

  int kb0 = qb - (WIN_ - 1);
  if (kb0 < 0) kb0 = 0;
  kb0 &= ~31;

  const int ksp = lane & 31, ksr = lane >> 5;
  const int vsp = lane & 3,  vsr = lane >> 2;

  for (int kb = kb0; kb < qb + 64; kb += 32) {
    __syncthreads();
#pragma unroll
    for (int i = 0; i < 4; ++i) {
      const int kl = w * 8 + 2 * i + ksr;
      gl2lds16(Kh + (size_t)(kb + kl) * QKVW + (ksp ^ (kl & 31)) * 8,
               &Ks[(w * 8 + 2 * i) * 256]);
    }
#pragma unroll
    for (int i = 0; i < 4; ++i) {
      const int dl = w * 64 + 16 * i + vsr;
      gl2lds16(Vh + (size_t)dl * S_ + kb + (vsp ^ ((dl >> 1) & 3)) * 8,
               &Vts[(w * 64 + 16 * i) * 32]);
    }
    __syncthreads();

    if (kb <= qw + 15 && kb + 31 >= qw - (WIN_ - 1)) {
      ushort_t* Pw = Ps[w];
#pragma unroll
      for (int kt = 0; kt < 2; ++kt) {
        floatx4 sacc = {};
        const int keyl = kt * 16 + l15;
        const int krow = keyl * 256;
        const int ksw = keyl & 31;
#pragma unroll
        for (int kd = 0; kd < 8; ++kd) {
          bf16x8 bk = *(const bf16x8*)&Ks[krow + ((kd * 4 + lq) ^ ksw) * 8];
          sacc = __builtin_amdgcn_mfma_f32_16x16x32_bf16(afq[kd], bk, sacc, 0, 0, 0);
        }
        const int keyg = kb + keyl;
#pragma unroll
        for (int r = 0; r < 4; ++r) {
          const int qg = qw + lq * 4 + r;
          const float t = __expf(sacc[r] * 0.04f);
          const float L = 50.f - __fdividef(100.f, t + 1.f);
          float p = __expf(L);
          p = (keyg <= qg && keyg >= qg - (WIN_ - 1)) ? p : 0.f;
          rs[r] += p;
          const int ql = lq * 4 + r;
          const int ch = kt * 2 + (l15 >> 3);
          Pw[ql * 32 + ((ch ^ ((ql >> 1) & 3)) * 8) + (l15 & 7)] = f2bf(p);
        }
      }
      asm volatile("s_waitcnt lgkmcnt(0)" ::: "memory");

      const bf16x8 bp = *(const bf16x8*)&Pw[l15 * 32 + ((lq ^ ((l15 >> 1) & 3)) * 8)];
      const int vsw = (l15 >> 1) & 3;
#pragma unroll
      for (int t = 0; t < 16; ++t) {
        bf16x8 av = *(const bf16x8*)&Vts[(t * 16 + l15) * 32 + ((lq ^ vsw) * 8)];
        acc[t] = __builtin_amdgcn_mfma_f32_16x16x32_bf16(av, bp, acc[t], 0, 0, 0);
      }
    }
  }

#pragma unroll
  for (int r = 0; r < 4; ++r) {
    rs[r] += __shfl_xor(rs[r], 1, 64);
    rs[r] += __shfl_xor(rs[r], 2, 64);
    rs[r] += __shfl_xor(rs[r], 4, 64);
    rs[r] += __shfl_xor(rs[r], 8, 64);
  }
  if (l15 == 0) {
#pragma unroll
    for (int r = 0; r < 4; ++r) rsb[w][lq * 4 + r] = rs[r];
  }
  asm volatile("s_waitcnt lgkmcnt(0)" ::: "memory");
  __builtin_amdgcn_wave_barrier();
  const float inv = 1.0f / rsb[w][l15];

  const size_t ob = ((size_t)(b * S_ + qw + l15) * NH_ + h) * HD_;
#pragma unroll
  for (int t = 0; t < 16; ++t) {
    ushort4 o;
    o.x = f2bf(acc[t][0] * inv);
    o.y = f2bf(acc[t][1] * inv);
    o.z = f2bf(acc[t][2] * inv);
    o.w = f2bf(acc[t][3] * inv);
    *(ushort4*)&AOb[ob + t * 16 + lq * 4] = o;
  }
}

// ---------------------------------------------------------------------------
extern "C" void kernel_launch(void* const* d_in, const int* in_sizes, int n_in,
                              void* d_out, int out_size, void* d_ws, size_t ws_size,
                              hipStream_t stream) {
  const float* X   = (const float*)d_in[0];
  const int*   pos = (const int*)d_in[2];
  const float* Wq  = (const float*)d_in[3];   // [2304, 2048]
  const float* Wk  = (const float*)d_in[4];   // [2304, 1024]
  const float* Wv  = (const float*)d_in[5];   // [2304, 1024]
  const float* Wo  = (const float*)d_in[6];   // [2048, 2304]
  float* out = (float*)d_out;

  const int M  = B_ * S_;        // 4096
  const int NQ = NH_ * HD_;      // 2048
  const int NK = NKV_ * HD_;     // 1024

  char* w = (char*)d_ws;
  ushort_t* QKV16 = (ushort_t*)w;  w += (size_t)M * QKVW * 2;          // 32 MB
  ushort_t* Xb    = (ushort_t*)w;  w += (size_t)M * H_ * 2;            // 18 MB
  ushort_t* Wqkvt = (ushort_t*)w;  w += (size_t)QKVW * H_ * 2;         // 18 MB
  ushort_t* Wot   = (ushort_t*)w;  w += (size_t)H_ * NQ * 2;           // 9.4 MB
  ushort_t* Vt16  = (ushort_t*)w;  w += (size_t)B_ * NKV_ * S_ * HD_ * 2;  // 8 MB
  ushort_t* AOb   = (ushort_t*)w;  w += (size_t)M * NQ * 2;            // 16 MB

  dim3 blk(256);

  cast_bf16<<<(M * H_) / 1024, blk, 0, stream>>>(X, Xb);
  // concatenated transposed QKV weights: rows [0,2048)=Wq^T, [2048,3072)=Wk^T, [3072,4096)=Wv^T
  transpose_cast<<<dim3(NQ / 32, H_ / 32), blk, 0, stream>>>(Wq, Wqkvt, H_, NQ);
  transpose_cast<<<dim3(NK / 32, H_ / 32), blk, 0, stream>>>(Wk, Wqkvt + (size_t)2048 * H_, H_, NK);
  transpose_cast<<<dim3(NK / 32, H_ / 32), blk, 0, stream>>>(Wv, Wqkvt + (size_t)3072 * H_, H_, NK);
  transpose_cast<<<dim3(H_ / 32, NQ / 32), blk, 0, stream>>>(Wo, Wot, NQ, H_);

  // fused QKV projection, bf16 out
  gemm_bt<true><<<dim3(QKVW / 128, M / 128), blk, 0, stream>>>(Xb, Wqkvt, QKV16, M, QKVW, H_);

  rope_inplace<<<dim3(M, 6), blk, 0, stream>>>(QKV16, pos);
  v_prep<<<dim3(S_ / 32, HD_ / 32, B_ * NKV_), blk, 0, stream>>>(QKV16, Vt16);

  attn_mfma<<<dim3(S_ / 64, NH_, B_), blk, 0, stream>>>(QKV16, Vt16, AOb);

  // output projection, fp32 out
  gemm_bt<false><<<dim3(H_ / 128, M / 128), blk, 0, stream>>>(AOb, Wot, out, M, H_, NQ);
}

// Round 5
// 406.428 us; speedup vs baseline: 7.2212x; 1.0336x over previous
//
#include <hip/hip_runtime.h>
#include <cmath>

#define B_   2
#define S_   2048
#define H_   2304
#define NH_  8
#define HD_  256
#define NKV_ 4
#define WIN_ 512
#define QKVW 4096   // fused QKV output row width (8+4+4 heads * 256)

typedef unsigned short ushort_t;
typedef __attribute__((ext_vector_type(8))) short bf16x8;     // 8 bf16 = 4 VGPRs
typedef __attribute__((ext_vector_type(4))) float floatx4;
typedef __attribute__((ext_vector_type(16))) float floatx16;

// round-to-nearest-even fp32 -> bf16
__device__ __forceinline__ unsigned short f2bf(float f) {
  unsigned u = __builtin_bit_cast(unsigned, f);
  u += 0x7fff + ((u >> 16) & 1);
  return (unsigned short)(u >> 16);
}
__device__ __forceinline__ float bf2f(ushort_t v) {
  unsigned u = (unsigned)v << 16;
  return __builtin_bit_cast(float, u);
}

// async global->LDS, 16 B per lane. LDS dest is wave-uniform base + lane*16.
__device__ __forceinline__ void gl2lds16(const void* g, void* l) {
  __builtin_amdgcn_global_load_lds(
      (const __attribute__((address_space(1))) unsigned int*)g,
      (__attribute__((address_space(3))) unsigned int*)l, 16, 0, 0);
}

// ---------------------------------------------------------------------------
// Elementwise fp32 -> bf16 cast (4 elems/thread).
// ---------------------------------------------------------------------------
__global__ void cast_bf16(const float* __restrict__ in, ushort_t* __restrict__ out) {
  const int i = blockIdx.x * 256 + threadIdx.x;
  float4 v = ((const float4*)in)[i];
  ushort4 o;
  o.x = f2bf(v.x); o.y = f2bf(v.y); o.z = f2bf(v.z); o.w = f2bf(v.w);
  ((ushort4*)out)[i] = o;
}

// ---------------------------------------------------------------------------
// W[K,N] fp32 -> Wt[N,K] bf16 (32x32 LDS tiles, 256 threads).
// ---------------------------------------------------------------------------
__global__ void transpose_cast(const float* __restrict__ W, ushort_t* __restrict__ Wt,
                               int K, int N) {
  __shared__ float t[32][33];
  const int lx = threadIdx.x & 31, ly = threadIdx.x >> 5;   // ly 0..7
  const int n0 = blockIdx.x * 32, k0 = blockIdx.y * 32;
#pragma unroll
  for (int i = 0; i < 4; ++i)
    t[ly + i * 8][lx] = W[(long long)(k0 + ly + i * 8) * N + n0 + lx];
  __syncthreads();
#pragma unroll
  for (int i = 0; i < 4; ++i)
    Wt[(long long)(n0 + ly + i * 8) * K + k0 + lx] = f2bf(t[lx][ly + i * 8]);
}

// ---------------------------------------------------------------------------
// bf16 MFMA GEMM, 32x32x16 variant: C[M,N] = A[M,K] @ Bt[N,K]^T.
// 128x128 tile, BK=32, 4 waves (2x2 of 64x64 each = 2x2 sub-tiles of 32x32),
// 8 MFMA + 8 ds_read_b128 per wave per K=32 (vs 16 MFMA with 16x16x32).
// XOR bank-swizzle: row m stores chunk c at slot c ^ ((m>>1)&3); 16-lane
// ds_read phases cover all 8 bank-quads 2-way (free, m136).
// A/B frag (32x32x16): m(or n)=lane&31, k=(lane>>5)*8 + j.
// C/D frag: col=lane&31, row=(reg&3)+8*(reg>>2)+4*(lane>>5)  [m74/m101].
// ---------------------------------------------------------------------------
template <bool OUT_BF16>
__launch_bounds__(256)
__global__ void gemm_bt(const ushort_t* __restrict__ A,   // [M,K] bf16
                        const ushort_t* __restrict__ Bt,  // [N,K] bf16
                        void* __restrict__ Cv, int M, int N, int K) {
  __shared__ ushort_t As[128 * 32];
  __shared__ ushort_t Bs[128 * 32];
  const int tid = threadIdx.x, lane = tid & 63, wid = tid >> 6;
  const int bm = blockIdx.y * 128, bn = blockIdx.x * 128;
  const int wm = (wid >> 1) * 64, wn = (wid & 1) * 64;

  floatx16 acc[2][2] = {};   // [mt][nt] 32x32 tiles

  // staging: lane -> (row r, chunk c); global col swizzled by key(r)
  const int r = lane >> 2, c = lane & 3;
  const int skey = (r >> 1) & 3;
  const int scol = (c ^ skey) * 8;
  const int srow = wid * 32 + r;
  const long long aBase = (long long)(bm + srow) * K + scol;
  const long long bBase = (long long)(bn + srow) * K + scol;
  ushort_t* AsW = &As[(wid * 32) * 32];
  ushort_t* BsW = &Bs[(wid * 32) * 32];

  const int l31 = lane & 31, lg = lane >> 5;
  const int swz = (l31 >> 1) & 3;

  for (int k0 = 0; k0 < K; k0 += 32) {
    __syncthreads();
    gl2lds16(A + aBase + k0,           AsW);
    gl2lds16(A + aBase + k0 + 16 * K,  AsW + 16 * 32);
    gl2lds16(Bt + bBase + k0,          BsW);
    gl2lds16(Bt + bBase + k0 + 16 * K, BsW + 16 * 32);
    __syncthreads();

    bf16x8 af[2][2], bfr[2][2];   // [tile][k-half]
#pragma unroll
    for (int mt = 0; mt < 2; ++mt)
#pragma unroll
      for (int h = 0; h < 2; ++h) {
        af[mt][h]  = *(const bf16x8*)&As[(wm + 32 * mt + l31) * 32 + ((2 * h + lg) ^ swz) * 8];
        bfr[mt][h] = *(const bf16x8*)&Bs[(wn + 32 * mt + l31) * 32 + ((2 * h + lg) ^ swz) * 8];
      }
#pragma unroll
    for (int h = 0; h < 2; ++h)
#pragma unroll
      for (int mt = 0; mt < 2; ++mt)
#pragma unroll
        for (int nt = 0; nt < 2; ++nt)
          acc[mt][nt] = __builtin_amdgcn_mfma_f32_32x32x16_bf16(af[mt][h], bfr[nt][h],
                                                                acc[mt][nt], 0, 0, 0);
  }

#pragma unroll
  for (int mt = 0; mt < 2; ++mt)
#pragma unroll
    for (int nt = 0; nt < 2; ++nt) {
      const int col = bn + wn + 32 * nt + l31;
#pragma unroll
      for (int g = 0; g < 4; ++g)
#pragma unroll
        for (int rr = 0; rr < 4; ++rr) {
          const int row = bm + wm + 32 * mt + rr + 8 * g + 4 * lg;
          const float v = acc[mt][nt][g * 4 + rr];
          if (OUT_BF16) ((ushort_t*)Cv)[(long long)row * N + col] = f2bf(v);
          else          ((float*)Cv)[(long long)row * N + col]    = v;
        }
    }
}

// ---------------------------------------------------------------------------
// In-place RoPE on QKV16 [B*S][4096] bf16 (Q cols 0..2047, K cols 2048..3071).
// Also folds the 1/16 attention scale into Q. V region untouched.
// ---------------------------------------------------------------------------
__global__ void rope_inplace(ushort_t* __restrict__ QKV16, const int* __restrict__ pos) {
  const int bs  = blockIdx.x;
  const int gid = blockIdx.y * 256 + threadIdx.x;
  const int head = gid >> 7;          // 0..11
  const int d    = gid & 127;
  const float pp   = (float)pos[bs];
  const float invf = __expf(-(float)d * (9.210340371976184f / 128.0f));
  const float ang  = pp * invf;
  const float cc = cosf(ang), sn = sinf(ang);
  ushort_t* base = QKV16 + (size_t)bs * QKVW + head * HD_;
  const float x1 = bf2f(base[d]);
  const float x2 = bf2f(base[d + 128]);
  float o1 = x1 * cc - x2 * sn;
  float o2 = x2 * cc + x1 * sn;
  if (head < NH_) { o1 *= 0.0625f; o2 *= 0.0625f; }   // fold 1/sqrt(256) into Q
  base[d]       = f2bf(o1);
  base[d + 128] = f2bf(o2);
}

// ---------------------------------------------------------------------------
// V transpose: QKV16 V region -> Vt16 [B][NKV][256][S] bf16.
// ---------------------------------------------------------------------------
__global__ void v_prep(const ushort_t* __restrict__ QKV16, ushort_t* __restrict__ Vt16) {
  __shared__ ushort_t tile[32][33];
  const int k0 = blockIdx.x * 32, d0 = blockIdx.y * 32;
  const int b = blockIdx.z >> 2, hk = blockIdx.z & 3;
  const int lx = threadIdx.x & 31, ly = threadIdx.x >> 5;
#pragma unroll
  for (int i = 0; i < 4; ++i)
    tile[ly + 8 * i][lx] =
        QKV16[(size_t)(b * S_ + k0 + ly + 8 * i) * QKVW + 3072 + hk * HD_ + d0 + lx];
  __syncthreads();
#pragma unroll
  for (int i = 0; i < 4; ++i)
    Vt16[((size_t)(b * NKV_ + hk) * HD_ + d0 + ly + 8 * i) * S_ + k0 + lx] =
        tile[lx][ly + 8 * i];
}

// ---------------------------------------------------------------------------
// MFMA flash attention, head-PAIR per block (both heads share hk's K/V).
// 512 threads = 8 waves: waves 0-3 -> head 2*hp, waves 4-7 -> head 2*hp+1.
// K/V staged ONCE per round and consumed by both heads (halves staging
// traffic vs one-head blocks). 64 queries x 32-key rounds; 16 q/wave.
// Softcapped logits in [-50,50] -> unnormalized exp accumulation, single
// normalization at the end. Attention kernel keeps 16x16x32 MFMA (verified).
// ---------------------------------------------------------------------------
__launch_bounds__(512)
__global__ void attn_mfma(const ushort_t* __restrict__ QKV16,  // [B*S][4096]
                          const ushort_t* __restrict__ Vt16,   // [B][NKV][256][S]
                          ushort_t* __restrict__ AOb) {        // [B][S][NH][256]
  __shared__ ushort_t Ks[32 * 256];    // [key][dim], chunk-swizzled
  __shared__ ushort_t Vts[256 * 32];   // [dim][key], chunk-swizzled
  __shared__ ushort_t Ps[8][16 * 32];  // per-wave P [q][key], chunk-swizzled
  __shared__ float rsb[8][16];

  const int lane = threadIdx.x & 63, w = threadIdx.x >> 6;   // w 0..7
  const int l15 = lane & 15, lq = lane >> 4;
  const int qb = blockIdx.x * 64;
  const int hp = blockIdx.y, b = blockIdx.z;                 // hp = hk
  const int h  = hp * 2 + (w >> 2);
  const int hw = w & 3;                                      // wave-in-head

  const ushort_t* Qh = QKV16 + (size_t)b * S_ * QKVW + h * HD_;
  const ushort_t* Kh = QKV16 + (size_t)b * S_ * QKVW + 2048 + hp * HD_;
  const ushort_t* Vh = Vt16 + ((size_t)(b * NKV_ + hp) * HD_) * S_;

  const int qw = qb + hw * 16;   // wave's first query

  bf16x8 afq[8];
  {
    const ushort_t* qr = Qh + (size_t)(qw + l15) * QKVW + lq * 8;
#pragma unroll
    for (int kd = 0; kd < 8; ++kd) afq[kd] = *(const bf16x8*)(qr + kd * 32);
  }

  floatx4 acc[16] = {};
  float rs[4] = {0.f, 0.f, 0.f, 0.f};

  int kb0 = qb - (WIN_ - 1);
  if (kb0 < 0) kb0 = 0;
  kb0 &= ~31;

  const int ksp = lane & 31, ksr = lane >> 5;
  const int vsp = lane & 3,  vsr = lane >> 2;

  for (int kb = kb0; kb < qb + 64; kb += 32) {
    __syncthreads();
    // stage K keys: wave w covers rows [w*4, w*4+4), 2 instrs x 2 rows
#pragma unroll
    for (int i = 0; i < 2; ++i) {
      const int kl = w * 4 + 2 * i + ksr;
      gl2lds16(Kh + (size_t)(kb + kl) * QKVW + (ksp ^ (kl & 31)) * 8,
               &Ks[(w * 4 + 2 * i) * 256]);
    }
    // stage V^T dims: wave w covers dims [w*32, w*32+32), 2 instrs x 16 rows
#pragma unroll
    for (int i = 0; i < 2; ++i) {
      const int dl = w * 32 + 16 * i + vsr;
      gl2lds16(Vh + (size_t)dl * S_ + kb + (vsp ^ ((dl >> 1) & 3)) * 8,
               &Vts[(w * 32 + 16 * i) * 32]);
    }
    __syncthreads();

    if (kb <= qw + 15 && kb + 31 >= qw - (WIN_ - 1)) {
      ushort_t* Pw = Ps[w];
#pragma unroll
      for (int kt = 0; kt < 2; ++kt) {
        floatx4 sacc = {};
        const int keyl = kt * 16 + l15;
        const int krow = keyl * 256;
        const int ksw = keyl & 31;
#pragma unroll
        for (int kd = 0; kd < 8; ++kd) {
          bf16x8 bk = *(const bf16x8*)&Ks[krow + ((kd * 4 + lq) ^ ksw) * 8];
          sacc = __builtin_amdgcn_mfma_f32_16x16x32_bf16(afq[kd], bk, sacc, 0, 0, 0);
        }
        const int keyg = kb + keyl;
#pragma unroll
        for (int rr = 0; rr < 4; ++rr) {
          const int qg = qw + lq * 4 + rr;
          const float t = __expf(sacc[rr] * 0.04f);
          const float L = 50.f - __fdividef(100.f, t + 1.f);
          float p = __expf(L);
          p = (keyg <= qg && keyg >= qg - (WIN_ - 1)) ? p : 0.f;
          rs[rr] += p;
          const int ql = lq * 4 + rr;
          const int ch = kt * 2 + (l15 >> 3);
          Pw[ql * 32 + ((ch ^ ((ql >> 1) & 3)) * 8) + (l15 & 7)] = f2bf(p);
        }
      }
      asm volatile("s_waitcnt lgkmcnt(0)" ::: "memory");

      const bf16x8 bp = *(const bf16x8*)&Pw[l15 * 32 + ((lq ^ ((l15 >> 1) & 3)) * 8)];
      const int vsw = (l15 >> 1) & 3;
#pragma unroll
      for (int t = 0; t < 16; ++t) {
        bf16x8 av = *(const bf16x8*)&Vts[(t * 16 + l15) * 32 + ((lq ^ vsw) * 8)];
        acc[t] = __builtin_amdgcn_mfma_f32_16x16x32_bf16(av, bp, acc[t], 0, 0, 0);
      }
    }
  }

#pragma unroll
  for (int rr = 0; rr < 4; ++rr) {
    rs[rr] += __shfl_xor(rs[rr], 1, 64);
    rs[rr] += __shfl_xor(rs[rr], 2, 64);
    rs[rr] += __shfl_xor(rs[rr], 4, 64);
    rs[rr] += __shfl_xor(rs[rr], 8, 64);
  }
  if (l15 == 0) {
#pragma unroll
    for (int rr = 0; rr < 4; ++rr) rsb[w][lq * 4 + rr] = rs[rr];
  }
  asm volatile("s_waitcnt lgkmcnt(0)" ::: "memory");
  __builtin_amdgcn_wave_barrier();
  const float inv = 1.0f / rsb[w][l15];

  const size_t ob = ((size_t)(b * S_ + qw + l15) * NH_ + h) * HD_;
#pragma unroll
  for (int t = 0; t < 16; ++t) {
    ushort4 o;
    o.x = f2bf(acc[t][0] * inv);
    o.y = f2bf(acc[t][1] * inv);
    o.z = f2bf(acc[t][2] * inv);
    o.w = f2bf(acc[t][3] * inv);
    *(ushort4*)&AOb[ob + t * 16 + lq * 4] = o;
  }
}

// ---------------------------------------------------------------------------
extern "C" void kernel_launch(void* const* d_in, const int* in_sizes, int n_in,
                              void* d_out, int out_size, void* d_ws, size_t ws_size,
                              hipStream_t stream) {
  const float* X   = (const float*)d_in[0];
  const int*   pos = (const int*)d_in[2];
  const float* Wq  = (const float*)d_in[3];   // [2304, 2048]
  const float* Wk  = (const float*)d_in[4];   // [2304, 1024]
  const float* Wv  = (const float*)d_in[5];   // [2304, 1024]
  const float* Wo  = (const float*)d_in[6];   // [2048, 2304]
  float* out = (float*)d_out;

  const int M  = B_ * S_;        // 4096
  const int NQ = NH_ * HD_;      // 2048
  const int NK = NKV_ * HD_;     // 1024

  char* w = (char*)d_ws;
  ushort_t* QKV16 = (ushort_t*)w;  w += (size_t)M * QKVW * 2;          // 32 MB
  ushort_t* Xb    = (ushort_t*)w;  w += (size_t)M * H_ * 2;            // 18 MB
  ushort_t* Wqkvt = (ushort_t*)w;  w += (size_t)QKVW * H_ * 2;         // 18 MB
  ushort_t* Wot   = (ushort_t*)w;  w += (size_t)H_ * NQ * 2;           // 9.4 MB
  ushort_t* Vt16  = (ushort_t*)w;  w += (size_t)B_ * NKV_ * S_ * HD_ * 2;  // 8 MB
  ushort_t* AOb   = (ushort_t*)w;  w += (size_t)M * NQ * 2;            // 16 MB

  dim3 blk(256);

  cast_bf16<<<(M * H_) / 1024, blk, 0, stream>>>(X, Xb);
  // concatenated transposed QKV weights: rows [0,2048)=Wq^T, [2048,3072)=Wk^T, [3072,4096)=Wv^T
  transpose_cast<<<dim3(NQ / 32, H_ / 32), blk, 0, stream>>>(Wq, Wqkvt, H_, NQ);
  transpose_cast<<<dim3(NK / 32, H_ / 32), blk, 0, stream>>>(Wk, Wqkvt + (size_t)2048 * H_, H_, NK);
  transpose_cast<<<dim3(NK / 32, H_ / 32), blk, 0, stream>>>(Wv, Wqkvt + (size_t)3072 * H_, H_, NK);
  transpose_cast<<<dim3(H_ / 32, NQ / 32), blk, 0, stream>>>(Wo, Wot, NQ, H_);

  // fused QKV projection, bf16 out
  gemm_bt<true><<<dim3(QKVW / 128, M / 128), blk, 0, stream>>>(Xb, Wqkvt, QKV16, M, QKVW, H_);

  rope_inplace<<<dim3(M, 6), blk, 0, stream>>>(QKV16, pos);
  v_prep<<<dim3(S_ / 32, HD_ / 32, B_ * NKV_), blk, 0, stream>>>(QKV16, Vt16);

  // attention: head-pair per block, 512 threads
  attn_mfma<<<dim3(S_ / 64, NKV_, B_), dim3(512), 0, stream>>>(QKV16, Vt16, AOb);

  // output projection, fp32 out
  gemm_bt<false><<<dim3(H_ / 128, M / 128), blk, 0, stream>>>(AOb, Wot, out, M, H_, NQ);
}

// Round 6
// 381.107 us; speedup vs baseline: 7.7010x; 1.0664x over previous
//
#include <hip/hip_runtime.h>
#include <cmath>

#define B_   2
#define S_   2048
#define H_   2304
#define NH_  8
#define HD_  256
#define NKV_ 4
#define WIN_ 512
#define QKVW 4096   // fused QKV output row width (8+4+4 heads * 256)

typedef unsigned short ushort_t;
typedef __attribute__((ext_vector_type(8))) short bf16x8;     // 8 bf16 = 4 VGPRs
typedef __attribute__((ext_vector_type(4))) float floatx4;

// round-to-nearest-even fp32 -> bf16
__device__ __forceinline__ unsigned short f2bf(float f) {
  unsigned u = __builtin_bit_cast(unsigned, f);
  u += 0x7fff + ((u >> 16) & 1);
  return (unsigned short)(u >> 16);
}
__device__ __forceinline__ float bf2f(ushort_t v) {
  unsigned u = (unsigned)v << 16;
  return __builtin_bit_cast(float, u);
}

// async global->LDS, 16 B per lane (still used by attention staging).
__device__ __forceinline__ void gl2lds16(const void* g, void* l) {
  __builtin_amdgcn_global_load_lds(
      (const __attribute__((address_space(1))) unsigned int*)g,
      (__attribute__((address_space(3))) unsigned int*)l, 16, 0, 0);
}

// ---------------------------------------------------------------------------
// Elementwise fp32 -> bf16 cast (4 elems/thread).
// ---------------------------------------------------------------------------
__global__ void cast_bf16(const float* __restrict__ in, ushort_t* __restrict__ out) {
  const int i = blockIdx.x * 256 + threadIdx.x;
  float4 v = ((const float4*)in)[i];
  ushort4 o;
  o.x = f2bf(v.x); o.y = f2bf(v.y); o.z = f2bf(v.z); o.w = f2bf(v.w);
  ((ushort4*)out)[i] = o;
}

// ---------------------------------------------------------------------------
// W[K,N] fp32 -> Wt[N,K] bf16 (32x32 LDS tiles, 256 threads).
// ---------------------------------------------------------------------------
__global__ void transpose_cast(const float* __restrict__ W, ushort_t* __restrict__ Wt,
                               int K, int N) {
  __shared__ float t[32][33];
  const int lx = threadIdx.x & 31, ly = threadIdx.x >> 5;   // ly 0..7
  const int n0 = blockIdx.x * 32, k0 = blockIdx.y * 32;
#pragma unroll
  for (int i = 0; i < 4; ++i)
    t[ly + i * 8][lx] = W[(long long)(k0 + ly + i * 8) * N + n0 + lx];
  __syncthreads();
#pragma unroll
  for (int i = 0; i < 4; ++i)
    Wt[(long long)(n0 + ly + i * 8) * K + k0 + lx] = f2bf(t[lx][ly + i * 8]);
}

// ---------------------------------------------------------------------------
// bf16 MFMA GEMM with REGISTER-DOUBLE-BUFFERED staging (pipeline past the
// m97 barrier-drain plateau): C[M,N] = A[M,K] @ Bt[N,K]^T.
// 128x128 tile, BK=64 (32 KB LDS), 4 waves (2x2 of 64x64), 16x16x32 MFMA.
//
// K-loop:   barrier; regs->LDS (vmcnt drain HERE, one compute-phase after
//           issue); barrier; issue global loads k+1 (no wait); 32 MFMA.
// Global-load latency is hidden behind the MFMA phase instead of being
// exposed at the pre-compute barrier (the global_load_lds structural stall).
//
// LDS swizzle (row = 64 elems = 128 B = 8 chunks = all 32 banks):
//   store chunk c of row m at slot c ^ (m&7);
//   frag read slot = (kk*4+lq) ^ (l15&7).
// Both writes and reads cover all 8 bank-quads per 8-lane phase.
// ---------------------------------------------------------------------------
template <bool OUT_BF16>
__launch_bounds__(256)
__global__ void gemm_bt(const ushort_t* __restrict__ A,   // [M,K] bf16
                        const ushort_t* __restrict__ Bt,  // [N,K] bf16
                        void* __restrict__ Cv, int M, int N, int K) {
  __shared__ ushort_t As[128 * 64];
  __shared__ ushort_t Bs[128 * 64];
  const int tid = threadIdx.x, lane = tid & 63, wid = tid >> 6;
  const int bm = blockIdx.y * 128, bn = blockIdx.x * 128;
  const int wm = (wid >> 1) * 64, wn = (wid & 1) * 64;

  floatx4 acc[4][4] = {};

  // staging: thread t -> row r = t>>1, chunks c = (t&1)*4 + i (i=0..3)
  const int r  = tid >> 1;
  const int cp = (tid & 1) * 4;
  const int wkey = r & 7;
  const ushort_t* Ap = A  + (long long)(bm + r) * K + cp * 8;
  const ushort_t* Bp = Bt + (long long)(bn + r) * K + cp * 8;
  ushort_t* Aw = &As[r * 64];
  ushort_t* Bw = &Bs[r * 64];

  const int l15 = lane & 15, lq = lane >> 4;
  const int rkey = l15 & 7;

  bf16x8 ar[4], br[4];
#pragma unroll
  for (int i = 0; i < 4; ++i) {             // prologue loads, k0 = 0
    ar[i] = *(const bf16x8*)(Ap + i * 8);
    br[i] = *(const bf16x8*)(Bp + i * 8);
  }

  for (int k0 = 0; k0 < K; k0 += 64) {
    __syncthreads();                         // prior iter's LDS reads done
#pragma unroll
    for (int i = 0; i < 4; ++i) {            // regs -> LDS (vmcnt drains here)
      *(bf16x8*)&Aw[((cp + i) ^ wkey) * 8] = ar[i];
      *(bf16x8*)&Bw[((cp + i) ^ wkey) * 8] = br[i];
    }
    __syncthreads();

    if (k0 + 64 < K) {                       // issue next tile, no wait
      const int kn = k0 + 64;
#pragma unroll
      for (int i = 0; i < 4; ++i) {
        ar[i] = *(const bf16x8*)(Ap + kn + i * 8);
        br[i] = *(const bf16x8*)(Bp + kn + i * 8);
      }
    }

#pragma unroll
    for (int kk = 0; kk < 2; ++kk) {
      bf16x8 af[4], bfr[4];
#pragma unroll
      for (int i = 0; i < 4; ++i) {
        af[i]  = *(const bf16x8*)&As[(wm + i * 16 + l15) * 64 + ((kk * 4 + lq) ^ rkey) * 8];
        bfr[i] = *(const bf16x8*)&Bs[(wn + i * 16 + l15) * 64 + ((kk * 4 + lq) ^ rkey) * 8];
      }
#pragma unroll
      for (int i = 0; i < 4; ++i)
#pragma unroll
        for (int j = 0; j < 4; ++j)
          acc[i][j] = __builtin_amdgcn_mfma_f32_16x16x32_bf16(af[i], bfr[j], acc[i][j], 0, 0, 0);
    }
  }

  const int r0 = lq * 4, c0 = l15;
#pragma unroll
  for (int i = 0; i < 4; ++i)
#pragma unroll
    for (int j = 0; j < 4; ++j) {
      const long long base = (long long)(bm + wm + i * 16 + r0) * N + bn + wn + j * 16 + c0;
      if (OUT_BF16) {
        ushort_t* Cp = (ushort_t*)Cv + base;
#pragma unroll
        for (int rr = 0; rr < 4; ++rr) Cp[(long long)rr * N] = f2bf(acc[i][j][rr]);
      } else {
        float* Cp = (float*)Cv + base;
#pragma unroll
        for (int rr = 0; rr < 4; ++rr) Cp[(long long)rr * N] = acc[i][j][rr];
      }
    }
}

// ---------------------------------------------------------------------------
// In-place RoPE on QKV16 [B*S][4096] bf16 (Q cols 0..2047, K cols 2048..3071).
// Also folds the 1/16 attention scale into Q. V region untouched.
// ---------------------------------------------------------------------------
__global__ void rope_inplace(ushort_t* __restrict__ QKV16, const int* __restrict__ pos) {
  const int bs  = blockIdx.x;
  const int gid = blockIdx.y * 256 + threadIdx.x;
  const int head = gid >> 7;          // 0..11
  const int d    = gid & 127;
  const float pp   = (float)pos[bs];
  const float invf = __expf(-(float)d * (9.210340371976184f / 128.0f));
  const float ang  = pp * invf;
  const float cc = cosf(ang), sn = sinf(ang);
  ushort_t* base = QKV16 + (size_t)bs * QKVW + head * HD_;
  const float x1 = bf2f(base[d]);
  const float x2 = bf2f(base[d + 128]);
  float o1 = x1 * cc - x2 * sn;
  float o2 = x2 * cc + x1 * sn;
  if (head < NH_) { o1 *= 0.0625f; o2 *= 0.0625f; }   // fold 1/sqrt(256) into Q
  base[d]       = f2bf(o1);
  base[d + 128] = f2bf(o2);
}

// ---------------------------------------------------------------------------
// V transpose: QKV16 V region -> Vt16 [B][NKV][256][S] bf16.
// ---------------------------------------------------------------------------
__global__ void v_prep(const ushort_t* __restrict__ QKV16, ushort_t* __restrict__ Vt16) {
  __shared__ ushort_t tile[32][33];
  const int k0 = blockIdx.x * 32, d0 = blockIdx.y * 32;
  const int b = blockIdx.z >> 2, hk = blockIdx.z & 3;
  const int lx = threadIdx.x & 31, ly = threadIdx.x >> 5;
#pragma unroll
  for (int i = 0; i < 4; ++i)
    tile[ly + 8 * i][lx] =
        QKV16[(size_t)(b * S_ + k0 + ly + 8 * i) * QKVW + 3072 + hk * HD_ + d0 + lx];
  __syncthreads();
#pragma unroll
  for (int i = 0; i < 4; ++i)
    Vt16[((size_t)(b * NKV_ + hk) * HD_ + d0 + ly + 8 * i) * S_ + k0 + lx] =
        tile[lx][ly + 8 * i];
}

// ---------------------------------------------------------------------------
// MFMA flash attention, head-PAIR per block (both heads share hk's K/V).
// 512 threads = 8 waves: waves 0-3 -> head 2*hp, waves 4-7 -> head 2*hp+1.
// ---------------------------------------------------------------------------
__launch_bounds__(512)
__global__ void attn_mfma(const ushort_t* __restrict__ QKV16,  // [B*S][4096]
                          const ushort_t* __restrict__ Vt16,   // [B][NKV][256][S]
                          ushort_t* __restrict__ AOb) {        // [B][S][NH][256]
  __shared__ ushort_t Ks[32 * 256];    // [key][dim], chunk-swizzled
  __shared__ ushort_t Vts[256 * 32];   // [dim][key], chunk-swizzled
  __shared__ ushort_t Ps[8][16 * 32];  // per-wave P [q][key], chunk-swizzled
  __shared__ float rsb[8][16];

  const int lane = threadIdx.x & 63, w = threadIdx.x >> 6;   // w 0..7
  const int l15 = lane & 15, lq = lane >> 4;
  const int qb = blockIdx.x * 64;
  const int hp = blockIdx.y, b = blockIdx.z;                 // hp = hk
  const int h  = hp * 2 + (w >> 2);
  const int hw = w & 3;                                      // wave-in-head

  const ushort_t* Qh = QKV16 + (size_t)b * S_ * QKVW + h * HD_;
  const ushort_t* Kh = QKV16 + (size_t)b * S_ * QKVW + 2048 + hp * HD_;
  const ushort_t* Vh = Vt16 + ((size_t)(b * NKV_ + hp) * HD_) * S_;

  const int qw = qb + hw * 16;   // wave's first query

  bf16x8 afq[8];
  {
    const ushort_t* qr = Qh + (size_t)(qw + l15) * QKVW + lq * 8;
#pragma unroll
    for (int kd = 0; kd < 8; ++kd) afq[kd] = *(const bf16x8*)(qr + kd * 32);
  }

  floatx4 acc[16] = {};
  float rs[4] = {0.f, 0.f, 0.f, 0.f};

  int kb0 = qb - (WIN_ - 1);
  if (kb0 < 0) kb0 = 0;
  kb0 &= ~31;

  const int ksp = lane & 31, ksr = lane >> 5;
  const int vsp = lane & 3,  vsr = lane >> 2;

  for (int kb = kb0; kb < qb + 64; kb += 32) {
    __syncthreads();
#pragma unroll
    for (int i = 0; i < 2; ++i) {
      const int kl = w * 4 + 2 * i + ksr;
      gl2lds16(Kh + (size_t)(kb + kl) * QKVW + (ksp ^ (kl & 31)) * 8,
               &Ks[(w * 4 + 2 * i) * 256]);
    }
#pragma unroll
    for (int i = 0; i < 2; ++i) {
      const int dl = w * 32 + 16 * i + vsr;
      gl2lds16(Vh + (size_t)dl * S_ + kb + (vsp ^ ((dl >> 1) & 3)) * 8,
               &Vts[(w * 32 + 16 * i) * 32]);
    }
    __syncthreads();

    if (kb <= qw + 15 && kb + 31 >= qw - (WIN_ - 1)) {
      ushort_t* Pw = Ps[w];
#pragma unroll
      for (int kt = 0; kt < 2; ++kt) {
        floatx4 sacc = {};
        const int keyl = kt * 16 + l15;
        const int krow = keyl * 256;
        const int ksw = keyl & 31;
#pragma unroll
        for (int kd = 0; kd < 8; ++kd) {
          bf16x8 bk = *(const bf16x8*)&Ks[krow + ((kd * 4 + lq) ^ ksw) * 8];
          sacc = __builtin_amdgcn_mfma_f32_16x16x32_bf16(afq[kd], bk, sacc, 0, 0, 0);
        }
        const int keyg = kb + keyl;
#pragma unroll
        for (int rr = 0; rr < 4; ++rr) {
          const int qg = qw + lq * 4 + rr;
          const float t = __expf(sacc[rr] * 0.04f);
          const float L = 50.f - __fdividef(100.f, t + 1.f);
          float p = __expf(L);
          p = (keyg <= qg && keyg >= qg - (WIN_ - 1)) ? p : 0.f;
          rs[rr] += p;
          const int ql = lq * 4 + rr;
          const int ch = kt * 2 + (l15 >> 3);
          Pw[ql * 32 + ((ch ^ ((ql >> 1) & 3)) * 8) + (l15 & 7)] = f2bf(p);
        }
      }
      asm volatile("s_waitcnt lgkmcnt(0)" ::: "memory");

      const bf16x8 bp = *(const bf16x8*)&Pw[l15 * 32 + ((lq ^ ((l15 >> 1) & 3)) * 8)];
      const int vsw = (l15 >> 1) & 3;
#pragma unroll
      for (int t = 0; t < 16; ++t) {
        bf16x8 av = *(const bf16x8*)&Vts[(t * 16 + l15) * 32 + ((lq ^ vsw) * 8)];
        acc[t] = __builtin_amdgcn_mfma_f32_16x16x32_bf16(av, bp, acc[t], 0, 0, 0);
      }
    }
  }

#pragma unroll
  for (int rr = 0; rr < 4; ++rr) {
    rs[rr] += __shfl_xor(rs[rr], 1, 64);
    rs[rr] += __shfl_xor(rs[rr], 2, 64);
    rs[rr] += __shfl_xor(rs[rr], 4, 64);
    rs[rr] += __shfl_xor(rs[rr], 8, 64);
  }
  if (l15 == 0) {
#pragma unroll
    for (int rr = 0; rr < 4; ++rr) rsb[w][lq * 4 + rr] = rs[rr];
  }
  asm volatile("s_waitcnt lgkmcnt(0)" ::: "memory");
  __builtin_amdgcn_wave_barrier();
  const float inv = 1.0f / rsb[w][l15];

  const size_t ob = ((size_t)(b * S_ + qw + l15) * NH_ + h) * HD_;
#pragma unroll
  for (int t = 0; t < 16; ++t) {
    ushort4 o;
    o.x = f2bf(acc[t][0] * inv);
    o.y = f2bf(acc[t][1] * inv);
    o.z = f2bf(acc[t][2] * inv);
    o.w = f2bf(acc[t][3] * inv);
    *(ushort4*)&AOb[ob + t * 16 + lq * 4] = o;
  }
}

// ---------------------------------------------------------------------------
extern "C" void kernel_launch(void* const* d_in, const int* in_sizes, int n_in,
                              void* d_out, int out_size, void* d_ws, size_t ws_size,
                              hipStream_t stream) {
  const float* X   = (const float*)d_in[0];
  const int*   pos = (const int*)d_in[2];
  const float* Wq  = (const float*)d_in[3];   // [2304, 2048]
  const float* Wk  = (const float*)d_in[4];   // [2304, 1024]
  const float* Wv  = (const float*)d_in[5];   // [2304, 1024]
  const float* Wo  = (const float*)d_in[6];   // [2048, 2304]
  float* out = (float*)d_out;

  const int M  = B_ * S_;        // 4096
  const int NQ = NH_ * HD_;      // 2048
  const int NK = NKV_ * HD_;     // 1024

  char* w = (char*)d_ws;
  ushort_t* QKV16 = (ushort_t*)w;  w += (size_t)M * QKVW * 2;          // 32 MB
  ushort_t* Xb    = (ushort_t*)w;  w += (size_t)M * H_ * 2;            // 18 MB
  ushort_t* Wqkvt = (ushort_t*)w;  w += (size_t)QKVW * H_ * 2;         // 18 MB
  ushort_t* Wot   = (ushort_t*)w;  w += (size_t)H_ * NQ * 2;           // 9.4 MB
  ushort_t* Vt16  = (ushort_t*)w;  w += (size_t)B_ * NKV_ * S_ * HD_ * 2;  // 8 MB
  ushort_t* AOb   = (ushort_t*)w;  w += (size_t)M * NQ * 2;            // 16 MB

  dim3 blk(256);

  cast_bf16<<<(M * H_) / 1024, blk, 0, stream>>>(X, Xb);
  // concatenated transposed QKV weights: rows [0,2048)=Wq^T, [2048,3072)=Wk^T, [3072,4096)=Wv^T
  transpose_cast<<<dim3(NQ / 32, H_ / 32), blk, 0, stream>>>(Wq, Wqkvt, H_, NQ);
  transpose_cast<<<dim3(NK / 32, H_ / 32), blk, 0, stream>>>(Wk, Wqkvt + (size_t)2048 * H_, H_, NK);
  transpose_cast<<<dim3(NK / 32, H_ / 32), blk, 0, stream>>>(Wv, Wqkvt + (size_t)3072 * H_, H_, NK);
  transpose_cast<<<dim3(H_ / 32, NQ / 32), blk, 0, stream>>>(Wo, Wot, NQ, H_);

  // fused QKV projection, bf16 out (K=2304 divisible by 64)
  gemm_bt<true><<<dim3(QKVW / 128, M / 128), blk, 0, stream>>>(Xb, Wqkvt, QKV16, M, QKVW, H_);

  rope_inplace<<<dim3(M, 6), blk, 0, stream>>>(QKV16, pos);
  v_prep<<<dim3(S_ / 32, HD_ / 32, B_ * NKV_), blk, 0, stream>>>(QKV16, Vt16);

  // attention: head-pair per block, 512 threads
  attn_mfma<<<dim3(S_ / 64, NKV_, B_), dim3(512), 0, stream>>>(QKV16, Vt16, AOb);

  // output projection, fp32 out (K=2048 divisible by 64)
  gemm_bt<false><<<dim3(H_ / 128, M / 128), blk, 0, stream>>>(AOb, Wot, out, M, H_, NQ);
}